// Round 1
// baseline (6884.450 us; speedup 1.0000x reference)
//
#include <hip/hip_runtime.h>
#include <hip/hip_bf16.h>
#include <math.h>

// Problem constants
#define Bc 2
#define Tc 1024
#define Dc 512
#define NHc 8
#define Lc 4
#define Ec 8
#define Kc 2
#define Hc 2048
#define HDc 64
#define Nc (Bc * Tc)   // 2048 tokens

// ---------------------------------------------------------------------------
// RMSNorm: one block per row
// ---------------------------------------------------------------------------
__global__ __launch_bounds__(256) void rmsnorm_kernel(
    const float* __restrict__ x, const float* __restrict__ w,
    float* __restrict__ y)
{
    int row = blockIdx.x;
    const float* xr = x + (size_t)row * Dc;
    __shared__ float red[256];
    int tid = threadIdx.x;
    float ss = 0.0f;
    for (int d = tid; d < Dc; d += 256) { float v = xr[d]; ss += v * v; }
    red[tid] = ss; __syncthreads();
    for (int s = 128; s > 0; s >>= 1) {
        if (tid < s) red[tid] += red[tid + s];
        __syncthreads();
    }
    float inv = rsqrtf(red[0] / (float)Dc + 1e-5f);
    for (int d = tid; d < Dc; d += 256)
        y[(size_t)row * Dc + d] = w[d] * xr[d] * inv;
}

// ---------------------------------------------------------------------------
// GEMM: C[M,N] (op)= A[M,K] @ W[N,K]^T
// mode 0: overwrite; mode 1: accumulate; mode 2: accumulate * rowScale[row]
// M,N multiples of 64; K multiple of 16.
// 64x64 tile, BK=16, 256 threads, 4x4 per thread.
// ---------------------------------------------------------------------------
#define BM 64
#define BN 64
#define BK 16
__global__ __launch_bounds__(256) void gemm_nt(
    const float* __restrict__ A, const float* __restrict__ W,
    float* __restrict__ C, int M, int N, int K,
    const float* __restrict__ rowScale, int mode)
{
    __shared__ float As[BK][BM];
    __shared__ float Ws[BK][BN];
    int tid = threadIdx.x;
    int m0 = blockIdx.y * BM;
    int n0 = blockIdx.x * BN;
    int tx = tid & 15, ty = tid >> 4;
    float acc[4][4] = {};

    int lr = tid >> 2;            // 0..63 (tile row to load)
    int lk = (tid & 3) * 4;       // 0,4,8,12 (k quad)

    for (int k0 = 0; k0 < K; k0 += BK) {
        float4 av = *(const float4*)(A + (size_t)(m0 + lr) * K + k0 + lk);
        As[lk + 0][lr] = av.x; As[lk + 1][lr] = av.y;
        As[lk + 2][lr] = av.z; As[lk + 3][lr] = av.w;
        float4 wv = *(const float4*)(W + (size_t)(n0 + lr) * K + k0 + lk);
        Ws[lk + 0][lr] = wv.x; Ws[lk + 1][lr] = wv.y;
        Ws[lk + 2][lr] = wv.z; Ws[lk + 3][lr] = wv.w;
        __syncthreads();
#pragma unroll
        for (int kk = 0; kk < BK; ++kk) {
            float a[4], b[4];
#pragma unroll
            for (int i = 0; i < 4; ++i) a[i] = As[kk][ty * 4 + i];
#pragma unroll
            for (int j = 0; j < 4; ++j) b[j] = Ws[kk][tx * 4 + j];
#pragma unroll
            for (int i = 0; i < 4; ++i)
#pragma unroll
                for (int j = 0; j < 4; ++j)
                    acc[i][j] += a[i] * b[j];
        }
        __syncthreads();
    }

#pragma unroll
    for (int i = 0; i < 4; ++i) {
        int r = m0 + ty * 4 + i;
        float s = 1.0f;
        if (mode == 2) {
            s = rowScale[r];
            if (s == 0.0f) continue;   // expert not selected for this token
        }
#pragma unroll
        for (int j = 0; j < 4; ++j) {
            int c = n0 + tx * 4 + j;
            size_t idx = (size_t)r * N + c;
            float v = acc[i][j] * s;
            if (mode == 0) C[idx] = v;
            else           C[idx] += v;
        }
    }
}

// ---------------------------------------------------------------------------
// RoPE in-place over q and k slices of qkv [N, 3*D]
// one thread per (token, head, pair)
// ---------------------------------------------------------------------------
__global__ __launch_bounds__(256) void rope_kernel(float* __restrict__ qkv)
{
    const int HD2 = HDc / 2;
    int idx = blockIdx.x * blockDim.x + threadIdx.x;
    int total = Nc * NHc * HD2;
    if (idx >= total) return;
    int i = idx % HD2;
    int hh = (idx / HD2) % NHc;
    int n = idx / (HD2 * NHc);
    int t = n % Tc;
    float invf = expf(-(2.0f * (float)i / (float)HDc) * logf(10000.0f));
    float f = (float)t * invf;
    float c = cosf(f), s = sinf(f);
    size_t base = (size_t)n * (3 * Dc) + (size_t)hh * HDc;
    float* qp = qkv + base;
    float* kp = qkv + base + Dc;
    float q1 = qp[i], q2 = qp[i + HD2];
    qp[i]       = q1 * c - q2 * s;
    qp[i + HD2] = q1 * s + q2 * c;
    float k1 = kp[i], k2 = kp[i + HD2];
    kp[i]       = k1 * c - k2 * s;
    kp[i + HD2] = k1 * s + k2 * c;
}

// ---------------------------------------------------------------------------
// Causal attention, one block per (q, b*NH+h). Scores live in LDS.
// ---------------------------------------------------------------------------
__global__ __launch_bounds__(256) void attn_kernel(
    const float* __restrict__ qkv, float* __restrict__ out)
{
    int qi = blockIdx.x;
    int bh = blockIdx.y;
    int b = bh / NHc, hh = bh % NHc;
    const int D3 = 3 * Dc;
    __shared__ float sQ[HDc];
    __shared__ float sS[Tc];
    __shared__ float red[256];
    int tid = threadIdx.x;

    const float* qrow = qkv + (size_t)(b * Tc + qi) * D3 + hh * HDc;
    if (tid < HDc) sQ[tid] = qrow[tid];
    __syncthreads();

    int nk = qi + 1;
    const float scale = 0.125f;  // 1/sqrt(64)
    for (int j = tid; j < nk; j += 256) {
        const float* krow = qkv + (size_t)(b * Tc + j) * D3 + Dc + hh * HDc;
        float dot = 0.0f;
#pragma unroll 16
        for (int d = 0; d < HDc; ++d) dot += sQ[d] * krow[d];
        sS[j] = dot * scale;
    }
    __syncthreads();

    // max
    float lm = -1e30f;
    for (int j = tid; j < nk; j += 256) lm = fmaxf(lm, sS[j]);
    red[tid] = lm; __syncthreads();
    for (int s = 128; s > 0; s >>= 1) {
        if (tid < s) red[tid] = fmaxf(red[tid], red[tid + s]);
        __syncthreads();
    }
    float m = red[0]; __syncthreads();

    // exp & sum
    float ls = 0.0f;
    for (int j = tid; j < nk; j += 256) {
        float p = expf(sS[j] - m);
        sS[j] = p; ls += p;
    }
    red[tid] = ls; __syncthreads();
    for (int s = 128; s > 0; s >>= 1) {
        if (tid < s) red[tid] += red[tid + s];
        __syncthreads();
    }
    float denom = red[0]; __syncthreads();

    // PV: dim d = tid&63, chunk = tid>>6 (4 chunks)
    int d = tid & 63, ch = tid >> 6;
    float acc = 0.0f;
    for (int j = ch; j < nk; j += 4) {
        const float* vrow = qkv + (size_t)(b * Tc + j) * D3 + 2 * Dc + hh * HDc;
        acc += sS[j] * vrow[d];
    }
    red[tid] = acc; __syncthreads();
    if (tid < 64) {
        float o = red[tid] + red[tid + 64] + red[tid + 128] + red[tid + 192];
        out[(size_t)(b * Tc + qi) * Dc + hh * HDc + d] = o / denom;
    }
}

// ---------------------------------------------------------------------------
// Router logits: one wave per token, 8 dot products of length 512
// ---------------------------------------------------------------------------
__global__ __launch_bounds__(64) void router_kernel(
    const float* __restrict__ x, const float* __restrict__ rw,
    float* __restrict__ logits)
{
    int n = blockIdx.x;
    int lane = threadIdx.x;
    const float* xr = x + (size_t)n * Dc;
    for (int e = 0; e < Ec; ++e) {
        const float* wr = rw + (size_t)e * Dc;
        float p = 0.0f;
        for (int d = lane; d < Dc; d += 64) p += xr[d] * wr[d];
        for (int off = 32; off > 0; off >>= 1) p += __shfl_down(p, off);
        if (lane == 0) logits[(size_t)n * Ec + e] = p;
    }
}

// ---------------------------------------------------------------------------
// Top-2 + softmax -> combine[E][N] (dense, zeros elsewhere)
// ---------------------------------------------------------------------------
__global__ __launch_bounds__(256) void topk_kernel(
    const float* __restrict__ logits, float* __restrict__ combine)
{
    int n = blockIdx.x * blockDim.x + threadIdx.x;
    if (n >= Nc) return;
    const float* lg = logits + (size_t)n * Ec;
    int i0 = -1, i1 = -1;
    float v0 = -1e30f, v1 = -1e30f;
    for (int e = 0; e < Ec; ++e) {
        float v = lg[e];
        if (v > v0) { v1 = v0; i1 = i0; v0 = v; i0 = e; }
        else if (v > v1) { v1 = v; i1 = e; }
    }
    float e1 = expf(v1 - v0);
    float w0 = 1.0f / (1.0f + e1);
    float w1 = e1 / (1.0f + e1);
    for (int e = 0; e < Ec; ++e)
        combine[(size_t)e * Nc + n] = (e == i0) ? w0 : ((e == i1) ? w1 : 0.0f);
}

// ---------------------------------------------------------------------------
// t = silu(g) * u, in-place over g
// ---------------------------------------------------------------------------
__global__ __launch_bounds__(256) void silumul_kernel(
    float* __restrict__ g, const float* __restrict__ u, int total)
{
    int i = blockIdx.x * blockDim.x + threadIdx.x;
    if (i >= total) return;
    float x = g[i];
    float s = x / (1.0f + expf(-x));
    g[i] = s * u[i];
}

// ---------------------------------------------------------------------------
// Host-side orchestration
// ---------------------------------------------------------------------------
extern "C" void kernel_launch(void* const* d_in, const int* in_sizes, int n_in,
                              void* d_out, int out_size, void* d_ws, size_t ws_size,
                              hipStream_t stream)
{
    const float* x        = (const float*)d_in[0];
    const float* qkv_w    = (const float*)d_in[1];
    const float* out_w    = (const float*)d_in[2];
    const float* norm1_w  = (const float*)d_in[3];
    const float* norm2_w  = (const float*)d_in[4];
    const float* router_w = (const float*)d_in[5];
    const float* moe_w1   = (const float*)d_in[6];
    const float* moe_w2   = (const float*)d_in[7];
    const float* moe_w3   = (const float*)d_in[8];
    const float* f_w1     = (const float*)d_in[9];
    const float* f_w2     = (const float*)d_in[10];
    const float* f_w3     = (const float*)d_in[11];
    const float* norm_f   = (const float*)d_in[12];
    float* out = (float*)d_out;

    float* p = (float*)d_ws;
    float* h       = p;  p += Nc * Dc;
    float* xn      = p;  p += Nc * Dc;
    float* qkv     = p;  p += Nc * 3 * Dc;
    float* attn    = p;  p += Nc * Dc;
    float* g1      = p;  p += Nc * Hc;
    float* g2      = p;  p += Nc * Hc;
    float* logits  = p;  p += Nc * Ec;
    float* combine = p;  p += Nc * Ec;

    hipMemcpyAsync(h, x, (size_t)Nc * Dc * sizeof(float),
                   hipMemcpyDeviceToDevice, stream);

    for (int l = 0; l < Lc; ++l) {
        // --- attention block ---
        rmsnorm_kernel<<<Nc, 256, 0, stream>>>(h, norm1_w + (size_t)l * Dc, xn);
        gemm_nt<<<dim3(3 * Dc / BN, Nc / BM), 256, 0, stream>>>(
            xn, qkv_w + (size_t)l * 3 * Dc * Dc, qkv, Nc, 3 * Dc, Dc, nullptr, 0);
        {
            int total = Nc * NHc * (HDc / 2);
            rope_kernel<<<(total + 255) / 256, 256, 0, stream>>>(qkv);
        }
        attn_kernel<<<dim3(Tc, Bc * NHc), 256, 0, stream>>>(qkv, attn);
        gemm_nt<<<dim3(Dc / BN, Nc / BM), 256, 0, stream>>>(
            attn, out_w + (size_t)l * Dc * Dc, h, Nc, Dc, Dc, nullptr, 1);

        // --- FFN block ---
        rmsnorm_kernel<<<Nc, 256, 0, stream>>>(h, norm2_w + (size_t)l * Dc, xn);
        if (l == 0 || l == 2) {
            int m = l / 2;
            router_kernel<<<Nc, 64, 0, stream>>>(
                xn, router_w + (size_t)m * Ec * Dc, logits);
            topk_kernel<<<(Nc + 255) / 256, 256, 0, stream>>>(logits, combine);
            for (int e = 0; e < Ec; ++e) {
                const float* w1 = moe_w1 + ((size_t)m * Ec + e) * Hc * Dc;
                const float* w2 = moe_w2 + ((size_t)m * Ec + e) * Dc * Hc;
                const float* w3 = moe_w3 + ((size_t)m * Ec + e) * Hc * Dc;
                gemm_nt<<<dim3(Hc / BN, Nc / BM), 256, 0, stream>>>(
                    xn, w1, g1, Nc, Hc, Dc, nullptr, 0);
                gemm_nt<<<dim3(Hc / BN, Nc / BM), 256, 0, stream>>>(
                    xn, w3, g2, Nc, Hc, Dc, nullptr, 0);
                silumul_kernel<<<(Nc * Hc + 255) / 256, 256, 0, stream>>>(
                    g1, g2, Nc * Hc);
                gemm_nt<<<dim3(Dc / BN, Nc / BM), 256, 0, stream>>>(
                    g1, w2, h, Nc, Dc, Hc, combine + (size_t)e * Nc, 2);
            }
        } else {
            int m = (l - 1) / 2;
            const float* w1 = f_w1 + (size_t)m * Hc * Dc;
            const float* w2 = f_w2 + (size_t)m * Dc * Hc;
            const float* w3 = f_w3 + (size_t)m * Hc * Dc;
            gemm_nt<<<dim3(Hc / BN, Nc / BM), 256, 0, stream>>>(
                xn, w1, g1, Nc, Hc, Dc, nullptr, 0);
            gemm_nt<<<dim3(Hc / BN, Nc / BM), 256, 0, stream>>>(
                xn, w3, g2, Nc, Hc, Dc, nullptr, 0);
            silumul_kernel<<<(Nc * Hc + 255) / 256, 256, 0, stream>>>(
                g1, g2, Nc * Hc);
            gemm_nt<<<dim3(Dc / BN, Nc / BM), 256, 0, stream>>>(
                g1, w2, h, Nc, Dc, Hc, nullptr, 1);
        }
    }

    rmsnorm_kernel<<<Nc, 256, 0, stream>>>(h, norm_f, out);
}

// Round 2
// 4723.275 us; speedup vs baseline: 1.4576x; 1.4576x over previous
//
#include <hip/hip_runtime.h>
#include <hip/hip_bf16.h>
#include <math.h>

// Problem constants
#define Bc 2
#define Tc 1024
#define Dc 512
#define NHc 8
#define Lc 4
#define Ec 8
#define Kc 2
#define Hc 2048
#define HDc 64
#define Nc (Bc * Tc)   // 2048 tokens

// ---------------------------------------------------------------------------
// RMSNorm: one block per row
// ---------------------------------------------------------------------------
__global__ __launch_bounds__(256) void rmsnorm_kernel(
    const float* __restrict__ x, const float* __restrict__ w,
    float* __restrict__ y)
{
    int row = blockIdx.x;
    const float* xr = x + (size_t)row * Dc;
    __shared__ float red[256];
    int tid = threadIdx.x;
    float ss = 0.0f;
    for (int d = tid; d < Dc; d += 256) { float v = xr[d]; ss += v * v; }
    red[tid] = ss; __syncthreads();
    for (int s = 128; s > 0; s >>= 1) {
        if (tid < s) red[tid] += red[tid + s];
        __syncthreads();
    }
    float inv = rsqrtf(red[0] / (float)Dc + 1e-5f);
    for (int d = tid; d < Dc; d += 256)
        y[(size_t)row * Dc + d] = w[d] * xr[d] * inv;
}

// ---------------------------------------------------------------------------
// GEMM: C[M,N] (op)= A[M,K] @ W[N,K]^T
// MODE 0: overwrite
// MODE 1: accumulate into C
// MODE 3: A rows gathered via tok[] (expert up-proj), compact C, early exit
// MODE 4: A compact, scatter C[tok[r]] += twt[r]*acc (expert down-proj)
// ---------------------------------------------------------------------------
#define BM 64
#define BN 64
#define BK 16
template<int MODE>
__global__ __launch_bounds__(256) void gemm_nt(
    const float* __restrict__ A, const float* __restrict__ W,
    float* __restrict__ C, int M, int N, int K,
    const int* __restrict__ tok, const float* __restrict__ twt,
    const int* __restrict__ countPtr)
{
    int count = M;
    if (MODE >= 3) {
        count = *countPtr;
        if ((int)(blockIdx.y * BM) >= count) return;
    }
    __shared__ float As[BK][BM];
    __shared__ float Ws[BK][BN];
    int tid = threadIdx.x;
    int m0 = blockIdx.y * BM;
    int n0 = blockIdx.x * BN;
    int tx = tid & 15, ty = tid >> 4;
    float acc[4][4] = {};

    int lr = tid >> 2;            // 0..63 (tile row to load)
    int lk = (tid & 3) * 4;       // 0,4,8,12 (k quad)

    // resolve A source row once
    size_t arow;
    if (MODE == 3) {
        int ar = m0 + lr;
        int t = (ar < count) ? tok[ar] : 0;
        arow = (size_t)t * K;
    } else {
        arow = (size_t)(m0 + lr) * K;
    }
    size_t wrow = (size_t)(n0 + lr) * K;

    for (int k0 = 0; k0 < K; k0 += BK) {
        float4 av = *(const float4*)(A + arow + k0 + lk);
        As[lk + 0][lr] = av.x; As[lk + 1][lr] = av.y;
        As[lk + 2][lr] = av.z; As[lk + 3][lr] = av.w;
        float4 wv = *(const float4*)(W + wrow + k0 + lk);
        Ws[lk + 0][lr] = wv.x; Ws[lk + 1][lr] = wv.y;
        Ws[lk + 2][lr] = wv.z; Ws[lk + 3][lr] = wv.w;
        __syncthreads();
#pragma unroll
        for (int kk = 0; kk < BK; ++kk) {
            float a[4], b[4];
#pragma unroll
            for (int i = 0; i < 4; ++i) a[i] = As[kk][ty * 4 + i];
#pragma unroll
            for (int j = 0; j < 4; ++j) b[j] = Ws[kk][tx * 4 + j];
#pragma unroll
            for (int i = 0; i < 4; ++i)
#pragma unroll
                for (int j = 0; j < 4; ++j)
                    acc[i][j] += a[i] * b[j];
        }
        __syncthreads();
    }

#pragma unroll
    for (int i = 0; i < 4; ++i) {
        int r = m0 + ty * 4 + i;
        if (MODE == 4) {
            if (r >= count) continue;
            int dest = tok[r];
            float w = twt[r];
#pragma unroll
            for (int j = 0; j < 4; ++j) {
                int c = n0 + tx * 4 + j;
                C[(size_t)dest * N + c] += w * acc[i][j];
            }
        } else {
#pragma unroll
            for (int j = 0; j < 4; ++j) {
                int c = n0 + tx * 4 + j;
                size_t idx = (size_t)r * N + c;
                if (MODE == 1) C[idx] += acc[i][j];
                else           C[idx] = acc[i][j];
            }
        }
    }
}

// ---------------------------------------------------------------------------
// RoPE in-place over q and k slices of qkv [N, 3*D]
// ---------------------------------------------------------------------------
__global__ __launch_bounds__(256) void rope_kernel(float* __restrict__ qkv)
{
    const int HD2 = HDc / 2;
    int idx = blockIdx.x * blockDim.x + threadIdx.x;
    int total = Nc * NHc * HD2;
    if (idx >= total) return;
    int i = idx % HD2;
    int hh = (idx / HD2) % NHc;
    int n = idx / (HD2 * NHc);
    int t = n % Tc;
    float invf = expf(-(2.0f * (float)i / (float)HDc) * logf(10000.0f));
    float f = (float)t * invf;
    float c = cosf(f), s = sinf(f);
    size_t base = (size_t)n * (3 * Dc) + (size_t)hh * HDc;
    float* qp = qkv + base;
    float* kp = qkv + base + Dc;
    float q1 = qp[i], q2 = qp[i + HD2];
    qp[i]       = q1 * c - q2 * s;
    qp[i + HD2] = q1 * s + q2 * c;
    float k1 = kp[i], k2 = kp[i + HD2];
    kp[i]       = k1 * c - k2 * s;
    kp[i + HD2] = k1 * s + k2 * c;
}

// ---------------------------------------------------------------------------
// Tiled causal attention, flash-style. Block = 256 threads, 64 queries of
// one (b,h). LDS: Q^T, K^T (reused for P), V. 4x4 register tile per thread.
// ---------------------------------------------------------------------------
__global__ __launch_bounds__(256) void attn_tiled(
    const float* __restrict__ qkv, float* __restrict__ out)
{
    __shared__ float sQ[64][65];   // [d][q]
    __shared__ float sKP[64][65];  // K: [d][j]; later P: [j][q]
    __shared__ float sV[64][65];   // [j][d]
    int qb = blockIdx.x, bh = blockIdx.y;
    int b = bh >> 3, hh = bh & 7;
    int tid = threadIdx.x;
    int tx = tid & 15, ty = tid >> 4;   // output 4x4 tile coords
    int lr = tid & 63, cw = tid >> 6;   // load: row, 16-dim chunk
    int d0 = cw * 16;
    const int D3 = 3 * Dc;
    const float* base = qkv + (size_t)b * Tc * D3 + (size_t)hh * HDc;

    // Load Q tile transposed -> sQ[d][q]
    {
        const float* qp = base + (size_t)(qb * 64 + lr) * D3 + d0;
        float tmp[16];
        *(float4*)&tmp[0]  = *(const float4*)(qp + 0);
        *(float4*)&tmp[4]  = *(const float4*)(qp + 4);
        *(float4*)&tmp[8]  = *(const float4*)(qp + 8);
        *(float4*)&tmp[12] = *(const float4*)(qp + 12);
#pragma unroll
        for (int k = 0; k < 16; ++k) sQ[d0 + k][lr] = tmp[k];
    }

    float o[4][4] = {};
    float mrow[4], lrowv[4];
#pragma unroll
    for (int i = 0; i < 4; ++i) { mrow[i] = -1e30f; lrowv[i] = 0.0f; }

    for (int kt = 0; kt <= qb; ++kt) {
        __syncthreads();   // prev iteration's sKP/sV reads complete
        // K tile transposed -> sKP[d][j]
        {
            const float* kp = base + (size_t)(kt * 64 + lr) * D3 + Dc + d0;
            float tmp[16];
            *(float4*)&tmp[0]  = *(const float4*)(kp + 0);
            *(float4*)&tmp[4]  = *(const float4*)(kp + 4);
            *(float4*)&tmp[8]  = *(const float4*)(kp + 8);
            *(float4*)&tmp[12] = *(const float4*)(kp + 12);
#pragma unroll
            for (int k = 0; k < 16; ++k) sKP[d0 + k][lr] = tmp[k];
        }
        // V tile natural -> sV[j][d]
        {
            const float* vp = base + (size_t)(kt * 64 + lr) * D3 + 2 * Dc + d0;
            float tmp[16];
            *(float4*)&tmp[0]  = *(const float4*)(vp + 0);
            *(float4*)&tmp[4]  = *(const float4*)(vp + 4);
            *(float4*)&tmp[8]  = *(const float4*)(vp + 8);
            *(float4*)&tmp[12] = *(const float4*)(vp + 12);
#pragma unroll
            for (int k = 0; k < 16; ++k) sV[lr][d0 + k] = tmp[k];
        }
        __syncthreads();

        // S = Q^T K  (4x4 per thread)
        float s[4][4] = {};
#pragma unroll 8
        for (int kk = 0; kk < 64; ++kk) {
            float a[4], bb[4];
#pragma unroll
            for (int i = 0; i < 4; ++i) a[i] = sQ[kk][ty * 4 + i];
#pragma unroll
            for (int j = 0; j < 4; ++j) bb[j] = sKP[kk][tx * 4 + j];
#pragma unroll
            for (int i = 0; i < 4; ++i)
#pragma unroll
                for (int j = 0; j < 4; ++j)
                    s[i][j] += a[i] * bb[j];
        }
        bool diag = (kt == qb);
#pragma unroll
        for (int i = 0; i < 4; ++i)
#pragma unroll
            for (int j = 0; j < 4; ++j) {
                s[i][j] *= 0.125f;
                if (diag && (tx * 4 + j > ty * 4 + i)) s[i][j] = -1e30f;
            }

        // online softmax per query row (reduce across the 16 tx lanes)
        float alpha[4];
#pragma unroll
        for (int i = 0; i < 4; ++i) {
            float rm = fmaxf(fmaxf(s[i][0], s[i][1]), fmaxf(s[i][2], s[i][3]));
            rm = fmaxf(rm, __shfl_xor(rm, 1));
            rm = fmaxf(rm, __shfl_xor(rm, 2));
            rm = fmaxf(rm, __shfl_xor(rm, 4));
            rm = fmaxf(rm, __shfl_xor(rm, 8));
            float mn = fmaxf(mrow[i], rm);
            alpha[i] = expf(mrow[i] - mn);
            mrow[i] = mn;
            float rs = 0.0f;
#pragma unroll
            for (int j = 0; j < 4; ++j) {
                float pv = expf(s[i][j] - mn);
                s[i][j] = pv;
                rs += pv;
            }
            rs += __shfl_xor(rs, 1);
            rs += __shfl_xor(rs, 2);
            rs += __shfl_xor(rs, 4);
            rs += __shfl_xor(rs, 8);
            lrowv[i] = lrowv[i] * alpha[i] + rs;
#pragma unroll
            for (int j = 0; j < 4; ++j) o[i][j] *= alpha[i];
        }

        __syncthreads();   // everyone done reading sKP as K
        // store P transposed -> sKP[j][q]
#pragma unroll
        for (int i = 0; i < 4; ++i)
#pragma unroll
            for (int j = 0; j < 4; ++j)
                sKP[tx * 4 + j][ty * 4 + i] = s[i][j];
        __syncthreads();

        // O += P V (4x4 per thread)
#pragma unroll 8
        for (int kk = 0; kk < 64; ++kk) {
            float a[4], bb[4];
#pragma unroll
            for (int i = 0; i < 4; ++i) a[i] = sKP[kk][ty * 4 + i];
#pragma unroll
            for (int j = 0; j < 4; ++j) bb[j] = sV[kk][tx * 4 + j];
#pragma unroll
            for (int i = 0; i < 4; ++i)
#pragma unroll
                for (int j = 0; j < 4; ++j)
                    o[i][j] += a[i] * bb[j];
        }
    }

#pragma unroll
    for (int i = 0; i < 4; ++i) {
        float inv = 1.0f / lrowv[i];
        int q = qb * 64 + ty * 4 + i;
#pragma unroll
        for (int j = 0; j < 4; ++j)
            out[(size_t)(b * Tc + q) * Dc + hh * HDc + tx * 4 + j] = o[i][j] * inv;
    }
}

// ---------------------------------------------------------------------------
// Router logits: one wave per token
// ---------------------------------------------------------------------------
__global__ __launch_bounds__(64) void router_kernel(
    const float* __restrict__ x, const float* __restrict__ rw,
    float* __restrict__ logits)
{
    int n = blockIdx.x;
    int lane = threadIdx.x;
    const float* xr = x + (size_t)n * Dc;
    for (int e = 0; e < Ec; ++e) {
        const float* wr = rw + (size_t)e * Dc;
        float p = 0.0f;
        for (int d = lane; d < Dc; d += 64) p += xr[d] * wr[d];
        for (int off = 32; off > 0; off >>= 1) p += __shfl_down(p, off);
        if (lane == 0) logits[(size_t)n * Ec + e] = p;
    }
}

__global__ void zero_counts_kernel(int* __restrict__ counts)
{
    if (threadIdx.x < Ec) counts[threadIdx.x] = 0;
}

// ---------------------------------------------------------------------------
// Top-2 + softmax -> per-expert token lists (tok/twt) via atomic counts
// ---------------------------------------------------------------------------
__global__ __launch_bounds__(256) void topk_build_kernel(
    const float* __restrict__ logits, int* __restrict__ counts,
    int* __restrict__ tok, float* __restrict__ twt)
{
    int n = blockIdx.x * blockDim.x + threadIdx.x;
    if (n >= Nc) return;
    const float* lg = logits + (size_t)n * Ec;
    int i0 = -1, i1 = -1;
    float v0 = -1e30f, v1 = -1e30f;
    for (int e = 0; e < Ec; ++e) {
        float v = lg[e];
        if (v > v0) { v1 = v0; i1 = i0; v0 = v; i0 = e; }
        else if (v > v1) { v1 = v; i1 = e; }
    }
    float e1 = expf(v1 - v0);
    float w0 = 1.0f / (1.0f + e1);
    float w1 = e1 / (1.0f + e1);
    int p0 = atomicAdd(&counts[i0], 1);
    tok[(size_t)i0 * Nc + p0] = n;
    twt[(size_t)i0 * Nc + p0] = w0;
    int p1 = atomicAdd(&counts[i1], 1);
    tok[(size_t)i1 * Nc + p1] = n;
    twt[(size_t)i1 * Nc + p1] = w1;
}

// ---------------------------------------------------------------------------
// t = silu(g) * u, in-place over g; rows >= count skipped
// ---------------------------------------------------------------------------
__global__ __launch_bounds__(256) void silumul_kernel(
    float* __restrict__ g, const float* __restrict__ u, int total,
    const int* __restrict__ countPtr)
{
    int i = blockIdx.x * blockDim.x + threadIdx.x;
    if (i >= total) return;
    if (countPtr) {
        int row = i >> 11;   // / Hc
        if (row >= *countPtr) return;
    }
    float x = g[i];
    float s = x / (1.0f + expf(-x));
    g[i] = s * u[i];
}

// ---------------------------------------------------------------------------
// Host-side orchestration
// ---------------------------------------------------------------------------
extern "C" void kernel_launch(void* const* d_in, const int* in_sizes, int n_in,
                              void* d_out, int out_size, void* d_ws, size_t ws_size,
                              hipStream_t stream)
{
    const float* x        = (const float*)d_in[0];
    const float* qkv_w    = (const float*)d_in[1];
    const float* out_w    = (const float*)d_in[2];
    const float* norm1_w  = (const float*)d_in[3];
    const float* norm2_w  = (const float*)d_in[4];
    const float* router_w = (const float*)d_in[5];
    const float* moe_w1   = (const float*)d_in[6];
    const float* moe_w2   = (const float*)d_in[7];
    const float* moe_w3   = (const float*)d_in[8];
    const float* f_w1     = (const float*)d_in[9];
    const float* f_w2     = (const float*)d_in[10];
    const float* f_w3     = (const float*)d_in[11];
    const float* norm_f   = (const float*)d_in[12];
    float* out = (float*)d_out;

    float* p = (float*)d_ws;
    float* h       = p;  p += Nc * Dc;
    float* xn      = p;  p += Nc * Dc;
    float* qkv     = p;  p += Nc * 3 * Dc;
    float* attn    = p;  p += Nc * Dc;
    float* g1      = p;  p += Nc * Hc;
    float* g2      = p;  p += Nc * Hc;
    float* logits  = p;  p += Nc * Ec;
    int*   counts  = (int*)p;   p += 16;
    int*   tok     = (int*)p;   p += Ec * Nc;
    float* twt     = p;         p += Ec * Nc;

    hipMemcpyAsync(h, x, (size_t)Nc * Dc * sizeof(float),
                   hipMemcpyDeviceToDevice, stream);

    for (int l = 0; l < Lc; ++l) {
        // --- attention block ---
        rmsnorm_kernel<<<Nc, 256, 0, stream>>>(h, norm1_w + (size_t)l * Dc, xn);
        gemm_nt<0><<<dim3(3 * Dc / BN, Nc / BM), 256, 0, stream>>>(
            xn, qkv_w + (size_t)l * 3 * Dc * Dc, qkv, Nc, 3 * Dc, Dc,
            nullptr, nullptr, nullptr);
        {
            int total = Nc * NHc * (HDc / 2);
            rope_kernel<<<(total + 255) / 256, 256, 0, stream>>>(qkv);
        }
        attn_tiled<<<dim3(Tc / 64, Bc * NHc), 256, 0, stream>>>(qkv, attn);
        gemm_nt<1><<<dim3(Dc / BN, Nc / BM), 256, 0, stream>>>(
            attn, out_w + (size_t)l * Dc * Dc, h, Nc, Dc, Dc,
            nullptr, nullptr, nullptr);

        // --- FFN block ---
        rmsnorm_kernel<<<Nc, 256, 0, stream>>>(h, norm2_w + (size_t)l * Dc, xn);
        if (l == 0 || l == 2) {
            int m = l / 2;
            router_kernel<<<Nc, 64, 0, stream>>>(
                xn, router_w + (size_t)m * Ec * Dc, logits);
            zero_counts_kernel<<<1, 64, 0, stream>>>(counts);
            topk_build_kernel<<<(Nc + 255) / 256, 256, 0, stream>>>(
                logits, counts, tok, twt);
            for (int e = 0; e < Ec; ++e) {
                const float* w1 = moe_w1 + ((size_t)m * Ec + e) * Hc * Dc;
                const float* w2 = moe_w2 + ((size_t)m * Ec + e) * Dc * Hc;
                const float* w3 = moe_w3 + ((size_t)m * Ec + e) * Hc * Dc;
                const int* tk = tok + (size_t)e * Nc;
                const float* tw = twt + (size_t)e * Nc;
                const int* cp = counts + e;
                gemm_nt<3><<<dim3(Hc / BN, Nc / BM), 256, 0, stream>>>(
                    xn, w1, g1, Nc, Hc, Dc, tk, nullptr, cp);
                gemm_nt<3><<<dim3(Hc / BN, Nc / BM), 256, 0, stream>>>(
                    xn, w3, g2, Nc, Hc, Dc, tk, nullptr, cp);
                silumul_kernel<<<(Nc * Hc + 255) / 256, 256, 0, stream>>>(
                    g1, g2, Nc * Hc, cp);
                gemm_nt<4><<<dim3(Dc / BN, Nc / BM), 256, 0, stream>>>(
                    g1, w2, h, Nc, Dc, Hc, tk, tw, cp);
            }
        } else {
            int m = (l - 1) / 2;
            const float* w1 = f_w1 + (size_t)m * Hc * Dc;
            const float* w2 = f_w2 + (size_t)m * Dc * Hc;
            const float* w3 = f_w3 + (size_t)m * Hc * Dc;
            gemm_nt<0><<<dim3(Hc / BN, Nc / BM), 256, 0, stream>>>(
                xn, w1, g1, Nc, Hc, Dc, nullptr, nullptr, nullptr);
            gemm_nt<0><<<dim3(Hc / BN, Nc / BM), 256, 0, stream>>>(
                xn, w3, g2, Nc, Hc, Dc, nullptr, nullptr, nullptr);
            silumul_kernel<<<(Nc * Hc + 255) / 256, 256, 0, stream>>>(
                g1, g2, Nc * Hc, nullptr);
            gemm_nt<1><<<dim3(Dc / BN, Nc / BM), 256, 0, stream>>>(
                g1, w2, h, Nc, Dc, Hc, nullptr, nullptr, nullptr);
        }
    }

    rmsnorm_kernel<<<Nc, 256, 0, stream>>>(h, norm_f, out);
}

// Round 5
// 3168.651 us; speedup vs baseline: 2.1727x; 1.4906x over previous
//
#include <hip/hip_runtime.h>
#include <hip/hip_bf16.h>
#include <math.h>

// Problem constants
#define Bc 2
#define Tc 1024
#define Dc 512
#define NHc 8
#define Lc 4
#define Ec 8
#define Kc 2
#define Hc 2048
#define HDc 64
#define Nc (Bc * Tc)   // 2048 tokens
#define NKc (Nc * Kc)  // 4096 compact MoE rows

typedef __bf16 bf16x8 __attribute__((ext_vector_type(8)));
typedef float  f32x4  __attribute__((ext_vector_type(4)));

__device__ inline unsigned short f2bf(float f) {
    union { float f; unsigned u; } v; v.f = f;
    unsigned r = v.u + 0x7FFFu + ((v.u >> 16) & 1u);   // RNE
    return (unsigned short)(r >> 16);
}
__device__ inline float bf2f(unsigned short b) {
    union { unsigned u; float f; } v; v.u = ((unsigned)b) << 16;
    return v.f;
}
// split a = hi + lo (each bf16); residual ~2^-17 relative
__device__ inline void splitbf(float a, unsigned short& hi, unsigned short& lo) {
    unsigned short h = f2bf(a);
    hi = h;
    lo = f2bf(a - bf2f(h));
}

// ---------------------------------------------------------------------------
// RMSNorm
// ---------------------------------------------------------------------------
__global__ __launch_bounds__(256) void rmsnorm_kernel(
    const float* __restrict__ x, const float* __restrict__ w,
    float* __restrict__ y)
{
    int row = blockIdx.x;
    const float* xr = x + (size_t)row * Dc;
    __shared__ float red[256];
    int tid = threadIdx.x;
    float ss = 0.0f;
    for (int d = tid; d < Dc; d += 256) { float v = xr[d]; ss += v * v; }
    red[tid] = ss; __syncthreads();
    for (int s = 128; s > 0; s >>= 1) {
        if (tid < s) red[tid] += red[tid + s];
        __syncthreads();
    }
    float inv = rsqrtf(red[0] / (float)Dc + 1e-5f);
    for (int d = tid; d < Dc; d += 256)
        y[(size_t)row * Dc + d] = w[d] * xr[d] * inv;
}

// ---------------------------------------------------------------------------
// bf16x3 MFMA GEMM: C[M,N] (op)= A[M,K] @ W[N,K]^T  at near-fp32 precision.
// A,W fp32 in global; split into bf16 hi/lo at LDS staging; 3 MFMAs per tile:
// Ah*Bh + Al*Bh + Ah*Bl.
// 128x128 tile, BK=32, 4 waves (2x2), wave does 64x64 via 4x4 16x16x32 MFMAs.
// MODE 0: C =       MODE 1: C +=
// MODE 5: A rows compact [offs..offs+count) (MoE t), W per expert (blockIdx.z),
//         scatter atomicAdd C[tok[r]] += twt[r]*v
// ---------------------------------------------------------------------------
template<int MODE>
__global__ __launch_bounds__(256) void gemm3(
    const float* __restrict__ A, const float* __restrict__ Wbase,
    float* __restrict__ C, int M, int N, int K,
    const int* __restrict__ tok, const float* __restrict__ twt,
    const int* __restrict__ counts, const int* __restrict__ offsets,
    size_t wstride)
{
    int e = (MODE == 5) ? blockIdx.z : 0;
    int count = M, offs = 0;
    if (MODE == 5) {
        count = counts[e];
        offs  = offsets[e];
        if ((int)(blockIdx.y * 128) >= count) return;
    }
    const float* W = Wbase + (size_t)e * wstride;

    __shared__ __align__(16) unsigned short Ah[128][32];
    __shared__ __align__(16) unsigned short Al[128][32];
    __shared__ __align__(16) unsigned short Bh[128][32];
    __shared__ __align__(16) unsigned short Bl[128][32];

    int tid = threadIdx.x;
    int m0 = blockIdx.y * 128, n0 = blockIdx.x * 128;
    int lrow = tid >> 3;          // 0..31
    int lcol = (tid & 7) * 4;     // 0..28

    int wave = tid >> 6, lane = tid & 63;
    int wm = wave >> 1, wn = wave & 1;
    int quad = lane >> 4, l16 = lane & 15;

    f32x4 acc[4][4];
#pragma unroll
    for (int mi = 0; mi < 4; ++mi)
#pragma unroll
        for (int ni = 0; ni < 4; ++ni)
            acc[mi][ni] = (f32x4){0.f, 0.f, 0.f, 0.f};

    for (int k0 = 0; k0 < K; k0 += 32) {
        if (k0) __syncthreads();
#pragma unroll
        for (int p = 0; p < 4; ++p) {
            int row = p * 32 + lrow;
            size_t arow;
            if (MODE == 5) {
                int rr = m0 + row; if (rr >= count) rr = 0;
                arow = (size_t)(offs + rr) * K;
            } else {
                arow = (size_t)(m0 + row) * K;
            }
            float4 av = *(const float4*)(A + arow + k0 + lcol);
            ushort4 h4, l4;
            splitbf(av.x, h4.x, l4.x); splitbf(av.y, h4.y, l4.y);
            splitbf(av.z, h4.z, l4.z); splitbf(av.w, h4.w, l4.w);
            *(ushort4*)&Ah[row][lcol] = h4;
            *(ushort4*)&Al[row][lcol] = l4;
            float4 wv = *(const float4*)(W + (size_t)(n0 + row) * K + k0 + lcol);
            splitbf(wv.x, h4.x, l4.x); splitbf(wv.y, h4.y, l4.y);
            splitbf(wv.z, h4.z, l4.z); splitbf(wv.w, h4.w, l4.w);
            *(ushort4*)&Bh[row][lcol] = h4;
            *(ushort4*)&Bl[row][lcol] = l4;
        }
        __syncthreads();

        bf16x8 ah[4], al[4], bh[4], bl[4];
#pragma unroll
        for (int mi = 0; mi < 4; ++mi) {
            ah[mi] = *(const bf16x8*)&Ah[wm * 64 + mi * 16 + l16][quad * 8];
            al[mi] = *(const bf16x8*)&Al[wm * 64 + mi * 16 + l16][quad * 8];
        }
#pragma unroll
        for (int ni = 0; ni < 4; ++ni) {
            bh[ni] = *(const bf16x8*)&Bh[wn * 64 + ni * 16 + l16][quad * 8];
            bl[ni] = *(const bf16x8*)&Bl[wn * 64 + ni * 16 + l16][quad * 8];
        }
#pragma unroll
        for (int mi = 0; mi < 4; ++mi)
#pragma unroll
            for (int ni = 0; ni < 4; ++ni) {
                acc[mi][ni] = __builtin_amdgcn_mfma_f32_16x16x32_bf16(
                    ah[mi], bh[ni], acc[mi][ni], 0, 0, 0);
                acc[mi][ni] = __builtin_amdgcn_mfma_f32_16x16x32_bf16(
                    al[mi], bh[ni], acc[mi][ni], 0, 0, 0);
                acc[mi][ni] = __builtin_amdgcn_mfma_f32_16x16x32_bf16(
                    ah[mi], bl[ni], acc[mi][ni], 0, 0, 0);
            }
    }

#pragma unroll
    for (int mi = 0; mi < 4; ++mi) {
#pragma unroll
        for (int ni = 0; ni < 4; ++ni) {
            int col = n0 + wn * 64 + ni * 16 + l16;
#pragma unroll
            for (int r = 0; r < 4; ++r) {
                int row = wm * 64 + mi * 16 + quad * 4 + r;
                float v = acc[mi][ni][r];
                if (MODE == 0) {
                    C[(size_t)(m0 + row) * N + col] = v;
                } else if (MODE == 1) {
                    C[(size_t)(m0 + row) * N + col] += v;
                } else {  // MODE 5
                    int rr = m0 + row;
                    if (rr < count) {
                        int dest = tok[offs + rr];
                        float w = twt[offs + rr];
                        atomicAdd(&C[(size_t)dest * N + col], w * v);
                    }
                }
            }
        }
    }
}

// ---------------------------------------------------------------------------
// Fused FFN up: t = silu(A@W1^T) * (A@W3^T), fp32 out, bf16x3 precision.
// 128 rows x 128 cols tile. GATHER: rows via tok[] (MoE, blockIdx.z=expert,
// compact output rows); else contiguous (dense).
// ---------------------------------------------------------------------------
template<bool GATHER>
__global__ __launch_bounds__(256) void ffn_fused(
    const float* __restrict__ A, const float* __restrict__ W1base,
    const float* __restrict__ W3base, float* __restrict__ T,
    int M, int N, int K,
    const int* __restrict__ tok, const int* __restrict__ counts,
    const int* __restrict__ offsets, size_t wstride)
{
    int e = GATHER ? blockIdx.z : 0;
    int count = M, offs = 0;
    if (GATHER) {
        count = counts[e];
        offs  = offsets[e];
        if ((int)(blockIdx.y * 128) >= count) return;
    }
    const float* W1 = W1base + (size_t)e * wstride;
    const float* W3 = W3base + (size_t)e * wstride;

    __shared__ __align__(16) unsigned short Ah[128][32];
    __shared__ __align__(16) unsigned short Al[128][32];
    __shared__ __align__(16) unsigned short B1h[128][32];
    __shared__ __align__(16) unsigned short B1l[128][32];
    __shared__ __align__(16) unsigned short B3h[128][32];
    __shared__ __align__(16) unsigned short B3l[128][32];
    __shared__ int sTok[128];

    int tid = threadIdx.x;
    int m0 = blockIdx.y * 128, n0 = blockIdx.x * 128;

    if (GATHER) {
        if (tid < 128) {
            int r = m0 + tid;
            sTok[tid] = (r < count) ? tok[offs + r] : tok[offs];
        }
        __syncthreads();
    }

    int lrow = tid >> 3;
    int lcol = (tid & 7) * 4;
    int wave = tid >> 6, lane = tid & 63;
    int wm = wave >> 1, wn = wave & 1;
    int quad = lane >> 4, l16 = lane & 15;

    f32x4 accg[4][4], accu[4][4];
#pragma unroll
    for (int mi = 0; mi < 4; ++mi)
#pragma unroll
        for (int ni = 0; ni < 4; ++ni) {
            accg[mi][ni] = (f32x4){0.f, 0.f, 0.f, 0.f};
            accu[mi][ni] = (f32x4){0.f, 0.f, 0.f, 0.f};
        }

    for (int k0 = 0; k0 < K; k0 += 32) {
        if (k0) __syncthreads();
#pragma unroll
        for (int p = 0; p < 4; ++p) {
            int row = p * 32 + lrow;
            size_t arow;
            if (GATHER) arow = (size_t)sTok[row] * K;
            else        arow = (size_t)(m0 + row) * K;
            float4 av = *(const float4*)(A + arow + k0 + lcol);
            ushort4 h4, l4;
            splitbf(av.x, h4.x, l4.x); splitbf(av.y, h4.y, l4.y);
            splitbf(av.z, h4.z, l4.z); splitbf(av.w, h4.w, l4.w);
            *(ushort4*)&Ah[row][lcol] = h4;
            *(ushort4*)&Al[row][lcol] = l4;
            size_t wr = (size_t)(n0 + row) * K + k0 + lcol;
            float4 w1v = *(const float4*)(W1 + wr);
            splitbf(w1v.x, h4.x, l4.x); splitbf(w1v.y, h4.y, l4.y);
            splitbf(w1v.z, h4.z, l4.z); splitbf(w1v.w, h4.w, l4.w);
            *(ushort4*)&B1h[row][lcol] = h4;
            *(ushort4*)&B1l[row][lcol] = l4;
            float4 w3v = *(const float4*)(W3 + wr);
            splitbf(w3v.x, h4.x, l4.x); splitbf(w3v.y, h4.y, l4.y);
            splitbf(w3v.z, h4.z, l4.z); splitbf(w3v.w, h4.w, l4.w);
            *(ushort4*)&B3h[row][lcol] = h4;
            *(ushort4*)&B3l[row][lcol] = l4;
        }
        __syncthreads();

        bf16x8 ah[4], al[4], bh[4], bl[4];
#pragma unroll
        for (int mi = 0; mi < 4; ++mi) {
            ah[mi] = *(const bf16x8*)&Ah[wm * 64 + mi * 16 + l16][quad * 8];
            al[mi] = *(const bf16x8*)&Al[wm * 64 + mi * 16 + l16][quad * 8];
        }
        // gate = A @ W1^T
#pragma unroll
        for (int ni = 0; ni < 4; ++ni) {
            bh[ni] = *(const bf16x8*)&B1h[wn * 64 + ni * 16 + l16][quad * 8];
            bl[ni] = *(const bf16x8*)&B1l[wn * 64 + ni * 16 + l16][quad * 8];
        }
#pragma unroll
        for (int mi = 0; mi < 4; ++mi)
#pragma unroll
            for (int ni = 0; ni < 4; ++ni) {
                accg[mi][ni] = __builtin_amdgcn_mfma_f32_16x16x32_bf16(
                    ah[mi], bh[ni], accg[mi][ni], 0, 0, 0);
                accg[mi][ni] = __builtin_amdgcn_mfma_f32_16x16x32_bf16(
                    al[mi], bh[ni], accg[mi][ni], 0, 0, 0);
                accg[mi][ni] = __builtin_amdgcn_mfma_f32_16x16x32_bf16(
                    ah[mi], bl[ni], accg[mi][ni], 0, 0, 0);
            }
        // up = A @ W3^T
#pragma unroll
        for (int ni = 0; ni < 4; ++ni) {
            bh[ni] = *(const bf16x8*)&B3h[wn * 64 + ni * 16 + l16][quad * 8];
            bl[ni] = *(const bf16x8*)&B3l[wn * 64 + ni * 16 + l16][quad * 8];
        }
#pragma unroll
        for (int mi = 0; mi < 4; ++mi)
#pragma unroll
            for (int ni = 0; ni < 4; ++ni) {
                accu[mi][ni] = __builtin_amdgcn_mfma_f32_16x16x32_bf16(
                    ah[mi], bh[ni], accu[mi][ni], 0, 0, 0);
                accu[mi][ni] = __builtin_amdgcn_mfma_f32_16x16x32_bf16(
                    al[mi], bh[ni], accu[mi][ni], 0, 0, 0);
                accu[mi][ni] = __builtin_amdgcn_mfma_f32_16x16x32_bf16(
                    ah[mi], bl[ni], accu[mi][ni], 0, 0, 0);
            }
    }

#pragma unroll
    for (int mi = 0; mi < 4; ++mi) {
#pragma unroll
        for (int ni = 0; ni < 4; ++ni) {
            int col = n0 + wn * 64 + ni * 16 + l16;
#pragma unroll
            for (int r = 0; r < 4; ++r) {
                int row = wm * 64 + mi * 16 + quad * 4 + r;
                float g = accg[mi][ni][r];
                float u = accu[mi][ni][r];
                float t = (g / (1.0f + expf(-g))) * u;
                if (GATHER) {
                    int rr = m0 + row;
                    if (rr < count) T[(size_t)(offs + rr) * N + col] = t;
                } else {
                    T[(size_t)(m0 + row) * N + col] = t;
                }
            }
        }
    }
}

// ---------------------------------------------------------------------------
// RoPE in-place over q,k slices of qkv [N, 3*D]
// ---------------------------------------------------------------------------
__global__ __launch_bounds__(256) void rope_kernel(float* __restrict__ qkv)
{
    const int HD2 = HDc / 2;
    int idx = blockIdx.x * blockDim.x + threadIdx.x;
    int total = Nc * NHc * HD2;
    if (idx >= total) return;
    int i = idx % HD2;
    int hh = (idx / HD2) % NHc;
    int n = idx / (HD2 * NHc);
    int t = n % Tc;
    float invf = expf(-(2.0f * (float)i / (float)HDc) * logf(10000.0f));
    float f = (float)t * invf;
    float c = cosf(f), s = sinf(f);
    size_t base = (size_t)n * (3 * Dc) + (size_t)hh * HDc;
    float* qp = qkv + base;
    float* kp = qkv + base + Dc;
    float q1 = qp[i], q2 = qp[i + HD2];
    qp[i]       = q1 * c - q2 * s;
    qp[i + HD2] = q1 * s + q2 * c;
    float k1 = kp[i], k2 = kp[i + HD2];
    kp[i]       = k1 * c - k2 * s;
    kp[i + HD2] = k1 * s + k2 * c;
}

// ---------------------------------------------------------------------------
// Tiled causal attention, flash-style (fp32, verified)
// ---------------------------------------------------------------------------
__global__ __launch_bounds__(256) void attn_tiled(
    const float* __restrict__ qkv, float* __restrict__ out)
{
    __shared__ float sQ[64][65];
    __shared__ float sKP[64][65];
    __shared__ float sV[64][65];
    int qb = blockIdx.x, bh = blockIdx.y;
    int b = bh >> 3, hh = bh & 7;
    int tid = threadIdx.x;
    int tx = tid & 15, ty = tid >> 4;
    int lr = tid & 63, cw = tid >> 6;
    int d0 = cw * 16;
    const int D3 = 3 * Dc;
    const float* base = qkv + (size_t)b * Tc * D3 + (size_t)hh * HDc;

    {
        const float* qp = base + (size_t)(qb * 64 + lr) * D3 + d0;
        float tmp[16];
        *(float4*)&tmp[0]  = *(const float4*)(qp + 0);
        *(float4*)&tmp[4]  = *(const float4*)(qp + 4);
        *(float4*)&tmp[8]  = *(const float4*)(qp + 8);
        *(float4*)&tmp[12] = *(const float4*)(qp + 12);
#pragma unroll
        for (int k = 0; k < 16; ++k) sQ[d0 + k][lr] = tmp[k];
    }

    float o[4][4] = {};
    float mrow[4], lrowv[4];
#pragma unroll
    for (int i = 0; i < 4; ++i) { mrow[i] = -1e30f; lrowv[i] = 0.0f; }

    for (int kt = 0; kt <= qb; ++kt) {
        __syncthreads();
        {
            const float* kp = base + (size_t)(kt * 64 + lr) * D3 + Dc + d0;
            float tmp[16];
            *(float4*)&tmp[0]  = *(const float4*)(kp + 0);
            *(float4*)&tmp[4]  = *(const float4*)(kp + 4);
            *(float4*)&tmp[8]  = *(const float4*)(kp + 8);
            *(float4*)&tmp[12] = *(const float4*)(kp + 12);
#pragma unroll
            for (int k = 0; k < 16; ++k) sKP[d0 + k][lr] = tmp[k];
        }
        {
            const float* vp = base + (size_t)(kt * 64 + lr) * D3 + 2 * Dc + d0;
            float tmp[16];
            *(float4*)&tmp[0]  = *(const float4*)(vp + 0);
            *(float4*)&tmp[4]  = *(const float4*)(vp + 4);
            *(float4*)&tmp[8]  = *(const float4*)(vp + 8);
            *(float4*)&tmp[12] = *(const float4*)(vp + 12);
#pragma unroll
            for (int k = 0; k < 16; ++k) sV[lr][d0 + k] = tmp[k];
        }
        __syncthreads();

        float s[4][4] = {};
#pragma unroll 8
        for (int kk = 0; kk < 64; ++kk) {
            float a[4], bb[4];
#pragma unroll
            for (int i = 0; i < 4; ++i) a[i] = sQ[kk][ty * 4 + i];
#pragma unroll
            for (int j = 0; j < 4; ++j) bb[j] = sKP[kk][tx * 4 + j];
#pragma unroll
            for (int i = 0; i < 4; ++i)
#pragma unroll
                for (int j = 0; j < 4; ++j)
                    s[i][j] += a[i] * bb[j];
        }
        bool diag = (kt == qb);
#pragma unroll
        for (int i = 0; i < 4; ++i)
#pragma unroll
            for (int j = 0; j < 4; ++j) {
                s[i][j] *= 0.125f;
                if (diag && (tx * 4 + j > ty * 4 + i)) s[i][j] = -1e30f;
            }

        float alpha[4];
#pragma unroll
        for (int i = 0; i < 4; ++i) {
            float rm = fmaxf(fmaxf(s[i][0], s[i][1]), fmaxf(s[i][2], s[i][3]));
            rm = fmaxf(rm, __shfl_xor(rm, 1));
            rm = fmaxf(rm, __shfl_xor(rm, 2));
            rm = fmaxf(rm, __shfl_xor(rm, 4));
            rm = fmaxf(rm, __shfl_xor(rm, 8));
            float mn = fmaxf(mrow[i], rm);
            alpha[i] = expf(mrow[i] - mn);
            mrow[i] = mn;
            float rs = 0.0f;
#pragma unroll
            for (int j = 0; j < 4; ++j) {
                float pv = expf(s[i][j] - mn);
                s[i][j] = pv;
                rs += pv;
            }
            rs += __shfl_xor(rs, 1);
            rs += __shfl_xor(rs, 2);
            rs += __shfl_xor(rs, 4);
            rs += __shfl_xor(rs, 8);
            lrowv[i] = lrowv[i] * alpha[i] + rs;
#pragma unroll
            for (int j = 0; j < 4; ++j) o[i][j] *= alpha[i];
        }

        __syncthreads();
#pragma unroll
        for (int i = 0; i < 4; ++i)
#pragma unroll
            for (int j = 0; j < 4; ++j)
                sKP[tx * 4 + j][ty * 4 + i] = s[i][j];
        __syncthreads();

#pragma unroll 8
        for (int kk = 0; kk < 64; ++kk) {
            float a[4], bb[4];
#pragma unroll
            for (int i = 0; i < 4; ++i) a[i] = sKP[kk][ty * 4 + i];
#pragma unroll
            for (int j = 0; j < 4; ++j) bb[j] = sV[kk][tx * 4 + j];
#pragma unroll
            for (int i = 0; i < 4; ++i)
#pragma unroll
                for (int j = 0; j < 4; ++j)
                    o[i][j] += a[i] * bb[j];
        }
    }

#pragma unroll
    for (int i = 0; i < 4; ++i) {
        float inv = 1.0f / lrowv[i];
        int q = qb * 64 + ty * 4 + i;
#pragma unroll
        for (int j = 0; j < 4; ++j)
            out[(size_t)(b * Tc + q) * Dc + hh * HDc + tx * 4 + j] = o[i][j] * inv;
    }
}

// ---------------------------------------------------------------------------
// Router logits: one wave per token
// ---------------------------------------------------------------------------
__global__ __launch_bounds__(64) void router_kernel(
    const float* __restrict__ x, const float* __restrict__ rw,
    float* __restrict__ logits)
{
    int n = blockIdx.x;
    int lane = threadIdx.x;
    const float* xr = x + (size_t)n * Dc;
    for (int e = 0; e < Ec; ++e) {
        const float* wr = rw + (size_t)e * Dc;
        float p = 0.0f;
        for (int d = lane; d < Dc; d += 64) p += xr[d] * wr[d];
        for (int off = 32; off > 0; off >>= 1) p += __shfl_down(p, off);
        if (lane == 0) logits[(size_t)n * Ec + e] = p;
    }
}

__global__ void zero8_kernel(int* __restrict__ counts)
{
    if (threadIdx.x < Ec) counts[threadIdx.x] = 0;
}

__global__ __launch_bounds__(256) void topk_count_kernel(
    const float* __restrict__ logits, int* __restrict__ counts,
    int2* __restrict__ eidx, float2* __restrict__ ewt)
{
    int n = blockIdx.x * blockDim.x + threadIdx.x;
    if (n >= Nc) return;
    const float* lg = logits + (size_t)n * Ec;
    int i0 = -1, i1 = -1;
    float v0 = -1e30f, v1 = -1e30f;
    for (int e = 0; e < Ec; ++e) {
        float v = lg[e];
        if (v > v0) { v1 = v0; i1 = i0; v0 = v; i0 = e; }
        else if (v > v1) { v1 = v; i1 = e; }
    }
    float e1 = expf(v1 - v0);
    float w0 = 1.0f / (1.0f + e1);
    float w1 = e1 / (1.0f + e1);
    atomicAdd(&counts[i0], 1);
    atomicAdd(&counts[i1], 1);
    eidx[n] = make_int2(i0, i1);
    ewt[n]  = make_float2(w0, w1);
}

__global__ void scan_kernel(int* __restrict__ counts, int* __restrict__ offsets)
{
    if (threadIdx.x == 0) {
        int s = 0;
        for (int e = 0; e < Ec; ++e) { offsets[e] = s; s += counts[e]; counts[e] = 0; }
    }
}

__global__ __launch_bounds__(256) void topk_place_kernel(
    const int2* __restrict__ eidx, const float2* __restrict__ ewt,
    int* __restrict__ counts, const int* __restrict__ offsets,
    int* __restrict__ tok, float* __restrict__ twt)
{
    int n = blockIdx.x * blockDim.x + threadIdx.x;
    if (n >= Nc) return;
    int2 ei = eidx[n];
    float2 w = ewt[n];
    int p0 = atomicAdd(&counts[ei.x], 1);
    int r0 = offsets[ei.x] + p0;
    tok[r0] = n; twt[r0] = w.x;
    int p1 = atomicAdd(&counts[ei.y], 1);
    int r1 = offsets[ei.y] + p1;
    tok[r1] = n; twt[r1] = w.y;
}

// ---------------------------------------------------------------------------
// Host-side orchestration
// ---------------------------------------------------------------------------
extern "C" void kernel_launch(void* const* d_in, const int* in_sizes, int n_in,
                              void* d_out, int out_size, void* d_ws, size_t ws_size,
                              hipStream_t stream)
{
    const float* x        = (const float*)d_in[0];
    const float* qkv_w    = (const float*)d_in[1];
    const float* out_w    = (const float*)d_in[2];
    const float* norm1_w  = (const float*)d_in[3];
    const float* norm2_w  = (const float*)d_in[4];
    const float* router_w = (const float*)d_in[5];
    const float* moe_w1   = (const float*)d_in[6];
    const float* moe_w2   = (const float*)d_in[7];
    const float* moe_w3   = (const float*)d_in[8];
    const float* f_w1     = (const float*)d_in[9];
    const float* f_w2     = (const float*)d_in[10];
    const float* f_w3     = (const float*)d_in[11];
    const float* norm_f   = (const float*)d_in[12];
    float* out = (float*)d_out;

    // workspace (~42 MB): h + xn + arena(NKc*Hc fp32) + routing misc
    float* p = (float*)d_ws;
    float* h      = p;  p += Nc * Dc;
    float* xn     = p;  p += Nc * Dc;
    float* arena  = p;  p += (size_t)NKc * Hc;   // 8.39M floats = 33.5 MB
    float* logits = p;  p += Nc * Ec;
    int*   counts  = (int*)p;  p += 16;
    int*   offsets = (int*)p;  p += 16;
    int2*  eidx    = (int2*)p; p += 2 * Nc;
    float* ewt     = p;        p += 2 * Nc;
    int*   tok     = (int*)p;  p += NKc;
    float* twt     = p;        p += NKc;

    float* qkv  = arena;   // [Nc][3*Dc] fp32, attention phase
    float* attn = xn;      // reuses xn after rmsnorm consumed
    float* t    = arena;   // [NKc][Hc] (MoE) or [Nc][Hc] (dense), FFN phase

    hipMemcpyAsync(h, x, (size_t)Nc * Dc * sizeof(float),
                   hipMemcpyDeviceToDevice, stream);

    for (int l = 0; l < Lc; ++l) {
        // --- attention block ---
        rmsnorm_kernel<<<Nc, 256, 0, stream>>>(h, norm1_w + (size_t)l * Dc, xn);
        gemm3<0><<<dim3(3 * Dc / 128, Nc / 128, 1), 256, 0, stream>>>(
            xn, qkv_w + (size_t)l * 3 * Dc * Dc, qkv, Nc, 3 * Dc, Dc,
            nullptr, nullptr, nullptr, nullptr, 0);
        {
            int total = Nc * NHc * (HDc / 2);
            rope_kernel<<<(total + 255) / 256, 256, 0, stream>>>(qkv);
        }
        attn_tiled<<<dim3(Tc / 64, Bc * NHc), 256, 0, stream>>>(qkv, attn);
        gemm3<1><<<dim3(Dc / 128, Nc / 128, 1), 256, 0, stream>>>(
            attn, out_w + (size_t)l * Dc * Dc, h, Nc, Dc, Dc,
            nullptr, nullptr, nullptr, nullptr, 0);

        // --- FFN block ---
        rmsnorm_kernel<<<Nc, 256, 0, stream>>>(h, norm2_w + (size_t)l * Dc, xn);
        if (l == 0 || l == 2) {
            int m = l / 2;
            router_kernel<<<Nc, 64, 0, stream>>>(
                xn, router_w + (size_t)m * Ec * Dc, logits);
            zero8_kernel<<<1, 64, 0, stream>>>(counts);
            topk_count_kernel<<<Nc / 256, 256, 0, stream>>>(
                logits, counts, eidx, (float2*)ewt);
            scan_kernel<<<1, 64, 0, stream>>>(counts, offsets);
            topk_place_kernel<<<Nc / 256, 256, 0, stream>>>(
                eidx, (float2*)ewt, counts, offsets, tok, twt);

            ffn_fused<true><<<dim3(Hc / 128, NKc / 128, Ec), 256, 0, stream>>>(
                xn, moe_w1 + (size_t)m * Ec * Hc * Dc,
                moe_w3 + (size_t)m * Ec * Hc * Dc, t, Nc, Hc, Dc,
                tok, counts, offsets, (size_t)Hc * Dc);
            gemm3<5><<<dim3(Dc / 128, NKc / 128, Ec), 256, 0, stream>>>(
                t, moe_w2 + (size_t)m * Ec * Dc * Hc, h, Nc, Dc, Hc,
                tok, twt, counts, offsets, (size_t)Dc * Hc);
        } else {
            int m = (l - 1) / 2;
            ffn_fused<false><<<dim3(Hc / 128, Nc / 128, 1), 256, 0, stream>>>(
                xn, f_w1 + (size_t)m * Hc * Dc, f_w3 + (size_t)m * Hc * Dc,
                t, Nc, Hc, Dc, nullptr, nullptr, nullptr, 0);
            gemm3<1><<<dim3(Dc / 128, Nc / 128, 1), 256, 0, stream>>>(
                t, f_w2 + (size_t)m * Dc * Hc, h, Nc, Dc, Hc,
                nullptr, nullptr, nullptr, nullptr, 0);
        }
    }

    rmsnorm_kernel<<<Nc, 256, 0, stream>>>(h, norm_f, out);
}